// Round 14
// baseline (217.459 us; speedup 1.0000x reference)
//
#include <hip/hip_runtime.h>
#include <math.h>

typedef float v2f __attribute__((ext_vector_type(2)));

constexpr int KW      = 56;
constexpr int NB      = 1792;
constexpr int QKV_CH  = 128;
constexpr int SIM_CH  = 24;
constexpr int SLOTS   = 64;     // atomic de-contention slots
constexpr int SMASK   = 63;
constexpr float EPS   = 1e-5f;

constexpr int   PA[10]  = {0,0,0,0,1,1,1,2,2,3};
constexpr int   PB[10]  = {0,1,2,3,1,2,3,2,3,3};
constexpr float PMf[10] = {1,2,2,2,1,2,2,1,2,1};

#if __has_builtin(__builtin_amdgcn_exp2f)
#define EXP2(x) __builtin_amdgcn_exp2f(x)
#else
#define EXP2(x) __expf((x) * 0.6931471805599453f)
#endif

__device__ inline unsigned bfr(float f) {            // fp32 -> bf16 (RNE)
    unsigned u = __float_as_uint(f);
    return (u + 0x7fffu + ((u >> 16) & 1u)) >> 16;
}
__device__ inline unsigned pk2(float a, float b) {   // {lo=a, hi=b}
    return bfr(a) | (bfr(b) << 16);
}
__device__ inline float blo(unsigned u) { return __uint_as_float(u << 16); }
__device__ inline float bhi(unsigned u) { return __uint_as_float(u & 0xffff0000u); }

// value-halving wave reduction step: literal constants only -> full unroll,
// static red[] indices (the R5/R6 loop form defeated unrolling -> scratch).
#define HTREE_STEP(M, HALF)                                         \
    {                                                               \
        const bool up_ = (lane & (M)) != 0;                         \
        _Pragma("unroll")                                           \
        for (int v = 0; v < (HALF); ++v) {                          \
            float a_ = up_ ? red[v + (HALF)] : red[v];              \
            float s_ = up_ ? red[v] : red[v + (HALF)];              \
            red[v] = a_ + __shfl_xor(s_, (M));                      \
        }                                                           \
    }

// ---- Kernel A: qkv (bf16-packed pairs) = w @ x + per-channel f32 stats;
// ---- blocks>=NB do table setup ----------------------------------------------
__global__ __launch_bounds__(256) void k_qkv(const float* __restrict__ x,
                                             const float* __restrict__ w,
                                             const float* __restrict__ rel,
                                             unsigned* __restrict__ qkvp,
                                             float* __restrict__ sums,
                                             float* __restrict__ tabs) {
    const int t = threadIdx.x;
    if (blockIdx.x >= NB) {
        // ---------- setup path: rel-derived tables (8 blocks) ----------
        const int t0 = (blockIdx.x - NB) * 256 + t;
        const int STR = 8 * 256;
        float* Rq  = tabs;
        float* Rk  = tabs + 224;
        float* E2q = tabs + 448;                // 56 x 12 (pad 2) = 672
        float* E2k = tabs + 1120;               // 672
        uint4* TQB = (uint4*)(tabs + 1792);     // 112 uint4: bf16 {tq0..3, tk0..3}
        uint4* TVB = (uint4*)(tabs + 2240);     // 112 uint4: bf16 {ta0..3, tb0..3}
        for (int idx = t0; idx < 448; idx += STR) {
            int which = idx / 224, r = idx % 224;
            int i = r >> 2, c = r & 3;
            const float* src = rel + (which * 4 + c) * 111;
            float s = 0.f;
            for (int tt = 0; tt < 56; ++tt) s += src[i + tt];
            (which ? Rk : Rq)[r] = s;
        }
        // E2 tables in padded 12-float rows (float4-aligned); pads = 0
        for (int idx = t0; idx < 1344; idx += STR) {
            int which = idx / 672, r = idx % 672;
            int i = r / 12, p = r % 12;
            float s = 0.f;
            if (p < 10) {
                const float* sa = rel + (which * 4 + PA[p]) * 111;
                const float* sb = rel + (which * 4 + PB[p]) * 111;
                for (int tt = 0; tt < 56; ++tt) s += sa[i + tt] * sb[i + tt];
            }
            (which ? E2k : E2q)[r] = s;
        }
        for (int d = t0; d < 112; d += STR) {
            bool v = d < 111;
            float4 tq, tk, ta, tb;
            tq.x = v ? rel[0 * 111 + d] : 0.f;
            tq.y = v ? rel[1 * 111 + d] : 0.f;
            tq.z = v ? rel[2 * 111 + d] : 0.f;
            tq.w = v ? rel[3 * 111 + d] : 0.f;
            tk.x = v ? rel[4 * 111 + 110 - d] : 0.f;
            tk.y = v ? rel[5 * 111 + 110 - d] : 0.f;
            tk.z = v ? rel[6 * 111 + 110 - d] : 0.f;
            tk.w = v ? rel[7 * 111 + 110 - d] : 0.f;
            ta.x = v ? rel[8 * 111 + d] : 0.f;
            ta.y = v ? rel[9 * 111 + d] : 0.f;
            ta.z = v ? rel[10 * 111 + d] : 0.f;
            ta.w = v ? rel[11 * 111 + d] : 0.f;
            tb.x = v ? rel[12 * 111 + d] : 0.f;
            tb.y = v ? rel[13 * 111 + d] : 0.f;
            tb.z = v ? rel[14 * 111 + d] : 0.f;
            tb.w = v ? rel[15 * 111 + d] : 0.f;
            TQB[d] = make_uint4(pk2(tq.x, tq.y), pk2(tq.z, tq.w),
                                pk2(tk.x, tk.y), pk2(tk.z, tk.w));
            TVB[d] = make_uint4(pk2(ta.x, ta.y), pk2(ta.z, ta.w),
                                pk2(tb.x, tb.y), pk2(tb.z, tb.w));
        }
        return;
    }
    // ---------- GEMM path ----------
    __shared__ float xs[64 * KW];
    __shared__ float wt[64 * 132];   // stride 132: kills 16-way bank conflict on
                                     // transpose-staging writes, keeps 16B align
    __shared__ float s1[128], s2[128];
    const int b = blockIdx.x;

    if (t < 128) { s1[t] = 0.f; s2[t] = 0.f; }
    for (int idx = t; idx < 896; idx += 256) {
        int c = idx / 14, r = idx % 14;
        float4 v = *(const float4*)&x[c * 100352 + b * 56 + r * 4];
        *(float4*)&xs[c * 56 + r * 4] = v;
    }
    for (int idx = t; idx < 2048; idx += 256) {
        int o = idx >> 4, cq = idx & 15;
        float4 v = *(const float4*)&w[o * 64 + cq * 4];
        wt[(cq * 4 + 0) * 132 + o] = v.x;
        wt[(cq * 4 + 1) * 132 + o] = v.y;
        wt[(cq * 4 + 2) * 132 + o] = v.z;
        wt[(cq * 4 + 3) * 132 + o] = v.w;
    }
    __syncthreads();

    if (t < 224) {
        const int ob = t & 31, ib = t >> 5;
        v2f acc[4][4];
#pragma unroll
        for (int o = 0; o < 4; ++o)
#pragma unroll
            for (int ip = 0; ip < 4; ++ip) acc[o][ip] = (v2f)(0.f);
        for (int c = 0; c < 64; ++c) {
            float4 wv = *(const float4*)&wt[c * 132 + (ob << 2)];
            float4 x0 = *(const float4*)&xs[c * 56 + (ib << 3)];
            float4 x1 = *(const float4*)&xs[c * 56 + (ib << 3) + 4];
            v2f xp[4];
            xp[0] = (v2f){x0.x, x0.y}; xp[1] = (v2f){x0.z, x0.w};
            xp[2] = (v2f){x1.x, x1.y}; xp[3] = (v2f){x1.z, x1.w};
            v2f wd[4];
            wd[0] = (v2f)(wv.x); wd[1] = (v2f)(wv.y);
            wd[2] = (v2f)(wv.z); wd[3] = (v2f)(wv.w);
#pragma unroll
            for (int o = 0; o < 4; ++o)
#pragma unroll
                for (int ip = 0; ip < 4; ++ip)
                    acc[o][ip] += wd[o] * xp[ip];
        }
        // bf16-pack the qkv row: uint j holds channels (2j, 2j+1)
#pragma unroll
        for (int i = 0; i < 8; ++i) {
            uint2 st;
            st.x = pk2(acc[0][i >> 1][i & 1], acc[1][i >> 1][i & 1]);
            st.y = pk2(acc[2][i >> 1][i & 1], acc[3][i >> 1][i & 1]);
            *(uint2*)&qkvp[b * 3584 + (ib * 8 + i) * 64 + ob * 2] = st;
        }
#pragma unroll
        for (int o = 0; o < 4; ++o) {
            float ps = 0.f, ps2 = 0.f;
#pragma unroll
            for (int ip = 0; ip < 4; ++ip) {
                ps  += acc[o][ip].x + acc[o][ip].y;
                ps2 += acc[o][ip].x * acc[o][ip].x + acc[o][ip].y * acc[o][ip].y;
            }
            atomicAdd(&s1[ob * 4 + o], ps);
            atomicAdd(&s2[ob * 4 + o], ps2);
        }
    }
    __syncthreads();
    if (t < 128) {
        float* dst = sums + (b & SMASK) * 256;
        atomicAdd(&dst[t], s1[t]);
        atomicAdd(&dst[128 + t], s2[t]);
    }
}

// ---------------- coef finalize: one 64-thread block per channel -------------
__global__ void k_coef(const float* __restrict__ sums, const float* __restrict__ g,
                       const float* __restrict__ bb, float* __restrict__ coef,
                       int nch, float invM) {
    const int o = blockIdx.x;
    const int s = threadIdx.x;          // 64 threads = 64 slots
    float a1 = sums[s * 2 * nch + o];
    float a2 = sums[s * 2 * nch + nch + o];
#pragma unroll
    for (int mk = 1; mk < 64; mk <<= 1) {
        a1 += __shfl_xor(a1, mk);
        a2 += __shfl_xor(a2, mk);
    }
    if (s == 0) {
        float mean = a1 * invM;
        float var  = fmaxf(a2 * invM - mean * mean, 0.f);
        float sc   = g[o] * rsqrtf(var + EPS);
        coef[o] = sc;
        coef[nch + o] = bb[o] - mean * sc;
    }
}

// ---------------- sim stats via Gram matrices (one wave per (b,g)) -----------
// q,k row a single uint4 of bf16 pairs; epilogue: explicit halving tree -------
__global__ __launch_bounds__(256) void k_simstats(const unsigned* __restrict__ qkvp,
                                                  const float* __restrict__ qcoef,
                                                  const float* __restrict__ Rq,
                                                  const float* __restrict__ Rk,
                                                  const float* __restrict__ E2q,
                                                  const float* __restrict__ E2k,
                                                  float* __restrict__ ssum) {
    __shared__ float Sst[4][32];
    const int wid = threadIdx.x >> 6, lane = threadIdx.x & 63;
    const int unit = blockIdx.x * 4 + wid;
    const int b = unit >> 3, g = unit & 7;
    const int iL = lane < 56 ? lane : 55;
    const float valid = lane < 56 ? 1.f : 0.f;

    uint4 A = *(const uint4*)(qkvp + b * 3584 + iL * 64 + g * 8);
    const float4 aq = *(const float4*)&qcoef[g * 16];
    const float4 ak = *(const float4*)&qcoef[g * 16 + 4];
    const float4 cq = *(const float4*)&qcoef[QKV_CH + g * 16];
    const float4 ck = *(const float4*)&qcoef[QKV_CH + g * 16 + 4];
    float qv[4], kv[4];
    qv[0] = (blo(A.x) * aq.x + cq.x) * valid;
    qv[1] = (bhi(A.x) * aq.y + cq.y) * valid;
    qv[2] = (blo(A.y) * aq.z + cq.z) * valid;
    qv[3] = (bhi(A.y) * aq.w + cq.w) * valid;
    kv[0] = (blo(A.z) * ak.x + ck.x) * valid;
    kv[1] = (bhi(A.z) * ak.y + ck.y) * valid;
    kv[2] = (blo(A.w) * ak.z + ck.z) * valid;
    kv[3] = (bhi(A.w) * ak.w + ck.w) * valid;

    float4 rq = *(const float4*)&Rq[iL * 4];
    float4 rk = *(const float4*)&Rk[iL * 4];
    float e2q[10], e2k[10];
    {
        float4 f0 = *(const float4*)&E2q[iL * 12];
        float4 f1 = *(const float4*)&E2q[iL * 12 + 4];
        float4 f2 = *(const float4*)&E2q[iL * 12 + 8];
        e2q[0] = f0.x; e2q[1] = f0.y; e2q[2] = f0.z; e2q[3] = f0.w;
        e2q[4] = f1.x; e2q[5] = f1.y; e2q[6] = f1.z; e2q[7] = f1.w;
        e2q[8] = f2.x; e2q[9] = f2.y;
        float4 h0 = *(const float4*)&E2k[iL * 12];
        float4 h1 = *(const float4*)&E2k[iL * 12 + 4];
        float4 h2 = *(const float4*)&E2k[iL * 12 + 8];
        e2k[0] = h0.x; e2k[1] = h0.y; e2k[2] = h0.z; e2k[3] = h0.w;
        e2k[4] = h1.x; e2k[5] = h1.y; e2k[6] = h1.z; e2k[7] = h1.w;
        e2k[8] = h2.x; e2k[9] = h2.y;
    }

    float red[32];
#pragma unroll
    for (int c = 0; c < 4; ++c) { red[c] = qv[c]; red[4 + c] = kv[c]; }
#pragma unroll
    for (int p = 0; p < 10; ++p) {
        red[8 + p]  = qv[PA[p]] * qv[PB[p]];
        red[18 + p] = kv[PA[p]] * kv[PB[p]];
    }
    {
        float rqa[4] = {rq.x, rq.y, rq.z, rq.w};
        float rka[4] = {rk.x, rk.y, rk.z, rk.w};
        float pq = 0.f, pk = 0.f, pq2 = 0.f, pk2_ = 0.f;
#pragma unroll
        for (int c = 0; c < 4; ++c) { pq += qv[c] * rqa[c]; pk += kv[c] * rka[c]; }
#pragma unroll
        for (int p = 0; p < 10; ++p) {
            pq2 += PMf[p] * red[8 + p]  * e2q[p];
            pk2_ += PMf[p] * red[18 + p] * e2k[p];
        }
        red[28] = pq; red[29] = pk; red[30] = pq2; red[31] = pk2_;
    }
    // explicit halving tree; lane L ends holding full sum of S[bitrev5(L&31)]
    HTREE_STEP(1, 16)
    HTREE_STEP(2, 8)
    HTREE_STEP(4, 4)
    HTREE_STEP(8, 2)
    HTREE_STEP(16, 1)
    red[0] += __shfl_xor(red[0], 32);
    const int vIdx = ((lane & 1) << 4) | ((lane & 2) << 2) | (lane & 4)
                   | ((lane & 8) >> 2) | ((lane & 16) >> 4);
    if (lane < 32) Sst[wid][vIdx] = red[0];
    __syncthreads();
    if (lane == 0) {
        float S[32];
#pragma unroll
        for (int q = 0; q < 8; ++q) {
            float4 f = *(const float4*)&Sst[wid][q * 4];
            S[q * 4] = f.x; S[q * 4 + 1] = f.y; S[q * 4 + 2] = f.z; S[q * 4 + 3] = f.w;
        }
        float sqk = S[0] * S[4] + S[1] * S[5] + S[2] * S[6] + S[3] * S[7];
        float sqk2 = 0.f;
#pragma unroll
        for (int p = 0; p < 10; ++p) sqk2 += PMf[p] * S[8 + p] * S[18 + p];
        float* ss = ssum + (blockIdx.x & SMASK) * 48;
        atomicAdd(&ss[g], sqk);
        atomicAdd(&ss[8 + g], 0.1f * S[28]);
        atomicAdd(&ss[16 + g], 0.1f * S[29]);
        atomicAdd(&ss[SIM_CH + g], sqk2);
        atomicAdd(&ss[SIM_CH + 8 + g], 0.01f * S[30]);
        atomicAdd(&ss[SIM_CH + 16 + g], 0.01f * S[31]);
    }
}

// ---- attention v13: bf16 score tables (1 strided read) unpacked into the
// ---- PRESERVED v2f tree (R8's failure was scalar-chaining, not bf16 itself);
// ---- bf16 sve tables; v2f sve accumulation; bf16-packed qkv in / {sv,sve} out
__global__ __launch_bounds__(256) void k_attn(const unsigned* __restrict__ qkvp,
                                              const float* __restrict__ qcoef,
                                              const float* __restrict__ scoef,
                                              const uint4* __restrict__ TQB,
                                              const uint4* __restrict__ TVB,
                                              unsigned* __restrict__ svp,
                                              float* __restrict__ osums) {
    __shared__ uint4  Tqk[112];        // bf16 {tq0..3, tk0..3}
    __shared__ uint4  Tvb[112];        // bf16 {ta0..3, tb0..3}
    __shared__ float4 KVs[4 * 168];    // per-wave: kh[56] | vh[56] | wh[56]
    const int t = threadIdx.x;
    const int wid = t >> 6, lane = t & 63;
    const int unit = blockIdx.x * 4 + wid;
    const int b = unit >> 3, g = unit & 7;
    const int iL = lane < 56 ? lane : 55;

    if (t < 112) { Tqk[t] = TQB[t]; Tvb[t] = TVB[t]; }

    const unsigned* rowp = qkvp + b * 3584 + iL * 64 + g * 8;
    uint4 A  = *(const uint4*)(rowp);        // q pairs, k pairs
    uint4 Bv = *(const uint4*)(rowp + 4);    // v pairs, w pairs
    const float4 a0 = *(const float4*)&qcoef[g * 16];
    const float4 a1 = *(const float4*)&qcoef[g * 16 + 4];
    const float4 a2 = *(const float4*)&qcoef[g * 16 + 8];
    const float4 a3 = *(const float4*)&qcoef[g * 16 + 12];
    const float4 c0 = *(const float4*)&qcoef[QKV_CH + g * 16];
    const float4 c1 = *(const float4*)&qcoef[QKV_CH + g * 16 + 4];
    const float4 c2 = *(const float4*)&qcoef[QKV_CH + g * 16 + 8];
    const float4 c3 = *(const float4*)&qcoef[QKV_CH + g * 16 + 12];
    float4 kh, vh, wh;
    kh.x = blo(A.z) * a1.x + c1.x;  kh.y = bhi(A.z) * a1.y + c1.y;
    kh.z = blo(A.w) * a1.z + c1.z;  kh.w = bhi(A.w) * a1.w + c1.w;
    vh.x = blo(Bv.x) * a2.x + c2.x; vh.y = bhi(Bv.x) * a2.y + c2.y;
    vh.z = blo(Bv.y) * a2.z + c2.z; vh.w = bhi(Bv.y) * a2.w + c2.w;
    wh.x = blo(Bv.z) * a3.x + c3.x; wh.y = bhi(Bv.z) * a3.y + c3.y;
    wh.z = blo(Bv.w) * a3.z + c3.z; wh.w = bhi(Bv.w) * a3.w + c3.w;
    float qh[4];
    qh[0] = blo(A.x) * a0.x + c0.x;  qh[1] = bhi(A.x) * a0.y + c0.y;
    qh[2] = blo(A.y) * a0.z + c0.z;  qh[3] = bhi(A.y) * a0.w + c0.w;

    // stage k/v/w for broadcast reads (lanes 56..63 duplicate slot 55: benign)
    KVs[wid * 168 + iL]       = kh;
    KVs[wid * 168 + 56 + iL]  = vh;
    KVs[wid * 168 + 112 + iL] = wh;
    __syncthreads();

    const float L2E = 1.44269504088896340736f;
    const float aqk = scoef[g] * L2E;
    const float aqr = scoef[8 + g] * 0.1f * L2E;
    const float akr = scoef[16 + g] * 0.1f * L2E;
    const float cc2 = (scoef[SIM_CH + g] + scoef[SIM_CH + 8 + g]
                       + scoef[SIM_CH + 16 + g]) * L2E;
    const v2f qa01 = {qh[0] * aqk, qh[1] * aqk};
    const v2f qa23 = {qh[2] * aqk, qh[3] * aqk};
    const v2f qr01 = {qh[0] * aqr, qh[1] * aqr};
    const v2f qr23 = {qh[2] * aqr, qh[3] * aqr};
    const v2f akrp = {akr, akr};

    float l = 0.f;
    v2f sva = (v2f)(0.f), svb = (v2f)(0.f), svc = (v2f)(0.f), svd = (v2f)(0.f);
    v2f sea = (v2f)(0.f), seb = (v2f)(0.f), sec = (v2f)(0.f), sed = (v2f)(0.f);

    const uint4*  Ap  = Tqk + 55 + iL;
    const uint4*  Bp  = Tvb + 55 + iL;
    const float4* kvp = KVs + wid * 168;

#pragma unroll 4
    for (int j = 0; j < 56; ++j) {
        uint4  Aq = Ap[-j];
        uint4  B  = Bp[-j];
        float4 kj = kvp[j];
        float4 vj = kvp[56 + j];
        float4 wj = kvp[112 + j];
        v2f tq01 = {blo(Aq.x), bhi(Aq.x)};
        v2f tq23 = {blo(Aq.y), bhi(Aq.y)};
        v2f tk01 = {blo(Aq.z), bhi(Aq.z)};
        v2f tk23 = {blo(Aq.w), bhi(Aq.w)};
        v2f u01 = akrp * tk01 + qa01;
        v2f u23 = akrp * tk23 + qa23;
        v2f acc = u01 * (v2f){kj.x, kj.y};
        acc += u23 * (v2f){kj.z, kj.w};
        acc += qr01 * tq01;
        acc += qr23 * tq23;
        float e = EXP2(acc.x + acc.y + cc2);
        l += e;
        v2f ep = {e, e};
        sva += ep * (v2f){vj.x, vj.y};
        svb += ep * (v2f){vj.z, vj.w};
        svc += ep * (v2f){wj.x, wj.y};
        svd += ep * (v2f){wj.z, wj.w};
        sea += ep * (v2f){blo(B.x), bhi(B.x)};
        seb += ep * (v2f){blo(B.y), bhi(B.y)};
        sec += ep * (v2f){blo(B.z), bhi(B.z)};
        sed += ep * (v2f){blo(B.w), bhi(B.w)};
    }
    const float inv = 1.f / l;
    const float inv1 = 0.1f * inv;
    float osv[8], ose[8];
    osv[0] = sva.x * inv;  osv[1] = sva.y * inv;
    osv[2] = svb.x * inv;  osv[3] = svb.y * inv;
    osv[4] = svc.x * inv;  osv[5] = svc.y * inv;
    osv[6] = svd.x * inv;  osv[7] = svd.y * inv;
    ose[0] = sea.x * inv1; ose[1] = sea.y * inv1;
    ose[2] = seb.x * inv1; ose[3] = seb.y * inv1;
    ose[4] = sec.x * inv1; ose[5] = sec.y * inv1;
    ose[6] = sed.x * inv1; ose[7] = sed.y * inv1;

    if (lane < 56) {
        size_t base = ((size_t)(g * 8) * 1792 + b) * 56 + iL;
#pragma unroll
        for (int c = 0; c < 8; ++c)
            svp[base + (size_t)c * 100352] = pk2(osv[c], ose[c]);
    }
    const float valid = lane < 56 ? 1.f : 0.f;
    float red[32];
#pragma unroll
    for (int c = 0; c < 8; ++c) {
        red[c]      = osv[c] * valid;
        red[8 + c]  = ose[c] * valid;
        red[16 + c] = osv[c] * osv[c] * valid;
        red[24 + c] = ose[c] * ose[c] * valid;
    }
    // explicit halving tree; lane L ends holding full sum of S[bitrev5(L&31)]
    HTREE_STEP(1, 16)
    HTREE_STEP(2, 8)
    HTREE_STEP(4, 4)
    HTREE_STEP(8, 2)
    HTREE_STEP(16, 1)
    red[0] += __shfl_xor(red[0], 32);
    if (lane < 32) {
        const int v = ((lane & 1) << 4) | ((lane & 2) << 2) | (lane & 4)
                    | ((lane & 8) >> 2) | ((lane & 16) >> 4);
        const int addr = ((v >> 4) & 1) * 128 + g * 16 + 2 * (v & 7) + ((v >> 3) & 1);
        float* dst = osums + (blockIdx.x & SMASK) * 256;
        atomicAdd(&dst[addr], red[0]);
    }
}

// ---- out: streaming affine combine from bf16-packed {sv,sve}, coalesced -----
__global__ __launch_bounds__(256) void k_out(const unsigned* __restrict__ svp,
                                             const float* __restrict__ ocoef,
                                             float* __restrict__ out) {
    int e4 = blockIdx.x * 256 + threadIdx.x;
    int i0 = e4 * 4;
    int oc = i0 / 100352;
    int o0 = 2 * oc;
    float A = ocoef[o0], B = ocoef[o0 + 1];
    float C = ocoef[QKV_CH + o0] + ocoef[QKV_CH + o0 + 1];
    uint4 p = *(const uint4*)&svp[i0];
    float4 r;
    r.x = A * blo(p.x) + B * bhi(p.x) + C;
    r.y = A * blo(p.y) + B * bhi(p.y) + C;
    r.z = A * blo(p.z) + B * bhi(p.z) + C;
    r.w = A * blo(p.w) + B * bhi(p.w) + C;
    *(float4*)&out[i0] = r;
}

extern "C" void kernel_launch(void* const* d_in, const int* in_sizes, int n_in,
                              void* d_out, int out_size, void* d_ws, size_t ws_size,
                              hipStream_t stream) {
    const float* x     = (const float*)d_in[0];
    const float* wqkv  = (const float*)d_in[1];
    const float* rel   = (const float*)d_in[2];
    const float* g_qkv = (const float*)d_in[3];
    const float* b_qkv = (const float*)d_in[4];
    const float* g_sim = (const float*)d_in[5];
    const float* b_sim = (const float*)d_in[6];
    const float* g_out = (const float*)d_in[7];
    const float* b_out = (const float*)d_in[8];
    float* out = (float*)d_out;
    float* ws = (float*)d_ws;

    unsigned* qkvp = (unsigned*)ws;             // bf16-packed qkv 6,422,528 uints
    unsigned* svp  = (unsigned*)(ws + 6422528); // packed {sv,sve}  6,422,528
    float* stats   = ws + 12845056;
    float* qkv_sums = stats;                    // 64 x 256 = 16384
    float* sim_sums = stats + 16384;            // 64 x 48  =  3072
    float* out_sums = stats + 19456;            // 64 x 256 = 16384  (ends 35840)
    float* qkv_coef = stats + 35840;            // 256
    float* sim_coef = stats + 36096;            // 48
    float* out_coef = stats + 36144;            // 256   (ends 36400)
    float* tabs     = stats + 36400;            // Rq(224) Rk(224) E2q(672) E2k(672)
                                                // TQB(448) TVB(448) = 2688
    float* Rq   = tabs;
    float* Rk   = tabs + 224;
    float* E2q  = tabs + 448;
    float* E2k  = tabs + 1120;
    uint4* TQB  = (uint4*)(tabs + 1792);
    uint4* TVB  = (uint4*)(tabs + 2240);

    // single upfront memset covers all three de-contended sum buffers
    hipMemsetAsync(stats, 0, 35840 * sizeof(float), stream);

    k_qkv<<<NB + 8, 256, 0, stream>>>(x, wqkv, rel, qkvp, qkv_sums, tabs);
    k_coef<<<QKV_CH, 64, 0, stream>>>(qkv_sums, g_qkv, b_qkv, qkv_coef, QKV_CH,
                                      1.0f / 100352.0f);
    k_simstats<<<3584, 256, 0, stream>>>(qkvp, qkv_coef, Rq, Rk, E2q, E2k,
                                         sim_sums);
    k_coef<<<SIM_CH, 64, 0, stream>>>(sim_sums, g_sim, b_sim, sim_coef, SIM_CH,
                                      1.0f / 5619712.0f);
    k_attn<<<3584, 256, 0, stream>>>(qkvp, qkv_coef, sim_coef, TQB, TVB,
                                     svp, out_sums);
    k_coef<<<QKV_CH, 64, 0, stream>>>(out_sums, g_out, b_out, out_coef, QKV_CH,
                                      1.0f / 100352.0f);
    k_out<<<6272, 256, 0, stream>>>(svp, out_coef, out);
}

// Round 15
// 215.788 us; speedup vs baseline: 1.0077x; 1.0077x over previous
//
#include <hip/hip_runtime.h>
#include <math.h>

typedef float v2f __attribute__((ext_vector_type(2)));

constexpr int KW      = 56;
constexpr int NB      = 1792;
constexpr int QKV_CH  = 128;
constexpr int SIM_CH  = 24;
constexpr int SLOTS   = 64;     // atomic de-contention slots
constexpr int SMASK   = 63;
constexpr float EPS   = 1e-5f;

constexpr int   PA[10]  = {0,0,0,0,1,1,1,2,2,3};
constexpr int   PB[10]  = {0,1,2,3,1,2,3,2,3,3};
constexpr float PMf[10] = {1,2,2,2,1,2,2,1,2,1};

#if __has_builtin(__builtin_amdgcn_exp2f)
#define EXP2(x) __builtin_amdgcn_exp2f(x)
#else
#define EXP2(x) __expf((x) * 0.6931471805599453f)
#endif

__device__ inline unsigned bfr(float f) {            // fp32 -> bf16 (RNE)
    unsigned u = __float_as_uint(f);
    return (u + 0x7fffu + ((u >> 16) & 1u)) >> 16;
}
__device__ inline unsigned pk2(float a, float b) {   // {lo=a, hi=b}
    return bfr(a) | (bfr(b) << 16);
}
__device__ inline float blo(unsigned u) { return __uint_as_float(u << 16); }
__device__ inline float bhi(unsigned u) { return __uint_as_float(u & 0xffff0000u); }

// value-halving wave reduction step: literal constants only -> full unroll,
// static red[] indices (the R5/R6 loop form defeated unrolling -> scratch).
#define HTREE_STEP(M, HALF)                                         \
    {                                                               \
        const bool up_ = (lane & (M)) != 0;                         \
        _Pragma("unroll")                                           \
        for (int v = 0; v < (HALF); ++v) {                          \
            float a_ = up_ ? red[v + (HALF)] : red[v];              \
            float s_ = up_ ? red[v] : red[v + (HALF)];              \
            red[v] = a_ + __shfl_xor(s_, (M));                      \
        }                                                           \
    }

// ---- Kernel A: qkv (bf16-packed pairs) = w @ x + per-channel f32 stats;
// ---- blocks>=NB do table setup ----------------------------------------------
__global__ __launch_bounds__(256) void k_qkv(const float* __restrict__ x,
                                             const float* __restrict__ w,
                                             const float* __restrict__ rel,
                                             unsigned* __restrict__ qkvp,
                                             float* __restrict__ sums,
                                             float* __restrict__ tabs) {
    const int t = threadIdx.x;
    if (blockIdx.x >= NB) {
        // ---------- setup path: rel-derived tables (8 blocks) ----------
        const int t0 = (blockIdx.x - NB) * 256 + t;
        const int STR = 8 * 256;
        float* Rq  = tabs;
        float* Rk  = tabs + 224;
        float* E2q = tabs + 448;                // 56 x 12 (pad 2) = 672
        float* E2k = tabs + 1120;               // 672
        float4* TQF = (float4*)(tabs + 1792);   // 224 float4: f32 q-tab / k-tab
        uint4*  TVB = (uint4*)(tabs + 2688);    // 112 uint4: bf16 {ta0..3, tb0..3}
        for (int idx = t0; idx < 448; idx += STR) {
            int which = idx / 224, r = idx % 224;
            int i = r >> 2, c = r & 3;
            const float* src = rel + (which * 4 + c) * 111;
            float s = 0.f;
            for (int tt = 0; tt < 56; ++tt) s += src[i + tt];
            (which ? Rk : Rq)[r] = s;
        }
        // E2 tables in padded 12-float rows (float4-aligned); pads = 0
        for (int idx = t0; idx < 1344; idx += STR) {
            int which = idx / 672, r = idx % 672;
            int i = r / 12, p = r % 12;
            float s = 0.f;
            if (p < 10) {
                const float* sa = rel + (which * 4 + PA[p]) * 111;
                const float* sb = rel + (which * 4 + PB[p]) * 111;
                for (int tt = 0; tt < 56; ++tt) s += sa[i + tt] * sb[i + tt];
            }
            (which ? E2k : E2q)[r] = s;
        }
        for (int d = t0; d < 112; d += STR) {
            bool v = d < 111;
            float4 tq, tk, ta, tb;
            tq.x = v ? rel[0 * 111 + d] : 0.f;
            tq.y = v ? rel[1 * 111 + d] : 0.f;
            tq.z = v ? rel[2 * 111 + d] : 0.f;
            tq.w = v ? rel[3 * 111 + d] : 0.f;
            tk.x = v ? rel[4 * 111 + 110 - d] : 0.f;
            tk.y = v ? rel[5 * 111 + 110 - d] : 0.f;
            tk.z = v ? rel[6 * 111 + 110 - d] : 0.f;
            tk.w = v ? rel[7 * 111 + 110 - d] : 0.f;
            ta.x = v ? rel[8 * 111 + d] : 0.f;
            ta.y = v ? rel[9 * 111 + d] : 0.f;
            ta.z = v ? rel[10 * 111 + d] : 0.f;
            ta.w = v ? rel[11 * 111 + d] : 0.f;
            tb.x = v ? rel[12 * 111 + d] : 0.f;
            tb.y = v ? rel[13 * 111 + d] : 0.f;
            tb.z = v ? rel[14 * 111 + d] : 0.f;
            tb.w = v ? rel[15 * 111 + d] : 0.f;
            TQF[d]       = tq;
            TQF[112 + d] = tk;
            TVB[d] = make_uint4(pk2(ta.x, ta.y), pk2(ta.z, ta.w),
                                pk2(tb.x, tb.y), pk2(tb.z, tb.w));
        }
        return;
    }
    // ---------- GEMM path ----------
    __shared__ float xs[64 * KW];
    __shared__ float wt[64 * 132];   // stride 132: kills 16-way bank conflict on
                                     // transpose-staging writes, keeps 16B align
    __shared__ float s1[128], s2[128];
    const int b = blockIdx.x;

    if (t < 128) { s1[t] = 0.f; s2[t] = 0.f; }
    for (int idx = t; idx < 896; idx += 256) {
        int c = idx / 14, r = idx % 14;
        float4 v = *(const float4*)&x[c * 100352 + b * 56 + r * 4];
        *(float4*)&xs[c * 56 + r * 4] = v;
    }
    for (int idx = t; idx < 2048; idx += 256) {
        int o = idx >> 4, cq = idx & 15;
        float4 v = *(const float4*)&w[o * 64 + cq * 4];
        wt[(cq * 4 + 0) * 132 + o] = v.x;
        wt[(cq * 4 + 1) * 132 + o] = v.y;
        wt[(cq * 4 + 2) * 132 + o] = v.z;
        wt[(cq * 4 + 3) * 132 + o] = v.w;
    }
    __syncthreads();

    if (t < 224) {
        const int ob = t & 31, ib = t >> 5;
        v2f acc[4][4];
#pragma unroll
        for (int o = 0; o < 4; ++o)
#pragma unroll
            for (int ip = 0; ip < 4; ++ip) acc[o][ip] = (v2f)(0.f);
        for (int c = 0; c < 64; ++c) {
            float4 wv = *(const float4*)&wt[c * 132 + (ob << 2)];
            float4 x0 = *(const float4*)&xs[c * 56 + (ib << 3)];
            float4 x1 = *(const float4*)&xs[c * 56 + (ib << 3) + 4];
            v2f xp[4];
            xp[0] = (v2f){x0.x, x0.y}; xp[1] = (v2f){x0.z, x0.w};
            xp[2] = (v2f){x1.x, x1.y}; xp[3] = (v2f){x1.z, x1.w};
            v2f wd[4];
            wd[0] = (v2f)(wv.x); wd[1] = (v2f)(wv.y);
            wd[2] = (v2f)(wv.z); wd[3] = (v2f)(wv.w);
#pragma unroll
            for (int o = 0; o < 4; ++o)
#pragma unroll
                for (int ip = 0; ip < 4; ++ip)
                    acc[o][ip] += wd[o] * xp[ip];
        }
        // bf16-pack the qkv row: uint j holds channels (2j, 2j+1)
#pragma unroll
        for (int i = 0; i < 8; ++i) {
            uint2 st;
            st.x = pk2(acc[0][i >> 1][i & 1], acc[1][i >> 1][i & 1]);
            st.y = pk2(acc[2][i >> 1][i & 1], acc[3][i >> 1][i & 1]);
            *(uint2*)&qkvp[b * 3584 + (ib * 8 + i) * 64 + ob * 2] = st;
        }
#pragma unroll
        for (int o = 0; o < 4; ++o) {
            float ps = 0.f, ps2 = 0.f;
#pragma unroll
            for (int ip = 0; ip < 4; ++ip) {
                ps  += acc[o][ip].x + acc[o][ip].y;
                ps2 += acc[o][ip].x * acc[o][ip].x + acc[o][ip].y * acc[o][ip].y;
            }
            atomicAdd(&s1[ob * 4 + o], ps);
            atomicAdd(&s2[ob * 4 + o], ps2);
        }
    }
    __syncthreads();
    if (t < 128) {
        float* dst = sums + (b & SMASK) * 256;
        atomicAdd(&dst[t], s1[t]);
        atomicAdd(&dst[128 + t], s2[t]);
    }
}

// ---------------- coef finalize: one 64-thread block per channel -------------
__global__ void k_coef(const float* __restrict__ sums, const float* __restrict__ g,
                       const float* __restrict__ bb, float* __restrict__ coef,
                       int nch, float invM) {
    const int o = blockIdx.x;
    const int s = threadIdx.x;          // 64 threads = 64 slots
    float a1 = sums[s * 2 * nch + o];
    float a2 = sums[s * 2 * nch + nch + o];
#pragma unroll
    for (int mk = 1; mk < 64; mk <<= 1) {
        a1 += __shfl_xor(a1, mk);
        a2 += __shfl_xor(a2, mk);
    }
    if (s == 0) {
        float mean = a1 * invM;
        float var  = fmaxf(a2 * invM - mean * mean, 0.f);
        float sc   = g[o] * rsqrtf(var + EPS);
        coef[o] = sc;
        coef[nch + o] = bb[o] - mean * sc;
    }
}

// ---------------- sim stats via Gram matrices (one wave per (b,g)) -----------
// q,k row a single uint4 of bf16 pairs; epilogue: explicit halving tree -------
__global__ __launch_bounds__(256) void k_simstats(const unsigned* __restrict__ qkvp,
                                                  const float* __restrict__ qcoef,
                                                  const float* __restrict__ Rq,
                                                  const float* __restrict__ Rk,
                                                  const float* __restrict__ E2q,
                                                  const float* __restrict__ E2k,
                                                  float* __restrict__ ssum) {
    __shared__ float Sst[4][32];
    const int wid = threadIdx.x >> 6, lane = threadIdx.x & 63;
    const int unit = blockIdx.x * 4 + wid;
    const int b = unit >> 3, g = unit & 7;
    const int iL = lane < 56 ? lane : 55;
    const float valid = lane < 56 ? 1.f : 0.f;

    uint4 A = *(const uint4*)(qkvp + b * 3584 + iL * 64 + g * 8);
    const float4 aq = *(const float4*)&qcoef[g * 16];
    const float4 ak = *(const float4*)&qcoef[g * 16 + 4];
    const float4 cq = *(const float4*)&qcoef[QKV_CH + g * 16];
    const float4 ck = *(const float4*)&qcoef[QKV_CH + g * 16 + 4];
    float qv[4], kv[4];
    qv[0] = (blo(A.x) * aq.x + cq.x) * valid;
    qv[1] = (bhi(A.x) * aq.y + cq.y) * valid;
    qv[2] = (blo(A.y) * aq.z + cq.z) * valid;
    qv[3] = (bhi(A.y) * aq.w + cq.w) * valid;
    kv[0] = (blo(A.z) * ak.x + ck.x) * valid;
    kv[1] = (bhi(A.z) * ak.y + ck.y) * valid;
    kv[2] = (blo(A.w) * ak.z + ck.z) * valid;
    kv[3] = (bhi(A.w) * ak.w + ck.w) * valid;

    float4 rq = *(const float4*)&Rq[iL * 4];
    float4 rk = *(const float4*)&Rk[iL * 4];
    float e2q[10], e2k[10];
    {
        float4 f0 = *(const float4*)&E2q[iL * 12];
        float4 f1 = *(const float4*)&E2q[iL * 12 + 4];
        float4 f2 = *(const float4*)&E2q[iL * 12 + 8];
        e2q[0] = f0.x; e2q[1] = f0.y; e2q[2] = f0.z; e2q[3] = f0.w;
        e2q[4] = f1.x; e2q[5] = f1.y; e2q[6] = f1.z; e2q[7] = f1.w;
        e2q[8] = f2.x; e2q[9] = f2.y;
        float4 h0 = *(const float4*)&E2k[iL * 12];
        float4 h1 = *(const float4*)&E2k[iL * 12 + 4];
        float4 h2 = *(const float4*)&E2k[iL * 12 + 8];
        e2k[0] = h0.x; e2k[1] = h0.y; e2k[2] = h0.z; e2k[3] = h0.w;
        e2k[4] = h1.x; e2k[5] = h1.y; e2k[6] = h1.z; e2k[7] = h1.w;
        e2k[8] = h2.x; e2k[9] = h2.y;
    }

    float red[32];
#pragma unroll
    for (int c = 0; c < 4; ++c) { red[c] = qv[c]; red[4 + c] = kv[c]; }
#pragma unroll
    for (int p = 0; p < 10; ++p) {
        red[8 + p]  = qv[PA[p]] * qv[PB[p]];
        red[18 + p] = kv[PA[p]] * kv[PB[p]];
    }
    {
        float rqa[4] = {rq.x, rq.y, rq.z, rq.w};
        float rka[4] = {rk.x, rk.y, rk.z, rk.w};
        float pq = 0.f, pk = 0.f, pq2 = 0.f, pk2_ = 0.f;
#pragma unroll
        for (int c = 0; c < 4; ++c) { pq += qv[c] * rqa[c]; pk += kv[c] * rka[c]; }
#pragma unroll
        for (int p = 0; p < 10; ++p) {
            pq2 += PMf[p] * red[8 + p]  * e2q[p];
            pk2_ += PMf[p] * red[18 + p] * e2k[p];
        }
        red[28] = pq; red[29] = pk; red[30] = pq2; red[31] = pk2_;
    }
    // explicit halving tree; lane L ends holding full sum of S[bitrev5(L&31)]
    HTREE_STEP(1, 16)
    HTREE_STEP(2, 8)
    HTREE_STEP(4, 4)
    HTREE_STEP(8, 2)
    HTREE_STEP(16, 1)
    red[0] += __shfl_xor(red[0], 32);
    const int vIdx = ((lane & 1) << 4) | ((lane & 2) << 2) | (lane & 4)
                   | ((lane & 8) >> 2) | ((lane & 16) >> 4);
    if (lane < 32) Sst[wid][vIdx] = red[0];
    __syncthreads();
    if (lane == 0) {
        float S[32];
#pragma unroll
        for (int q = 0; q < 8; ++q) {
            float4 f = *(const float4*)&Sst[wid][q * 4];
            S[q * 4] = f.x; S[q * 4 + 1] = f.y; S[q * 4 + 2] = f.z; S[q * 4 + 3] = f.w;
        }
        float sqk = S[0] * S[4] + S[1] * S[5] + S[2] * S[6] + S[3] * S[7];
        float sqk2 = 0.f;
#pragma unroll
        for (int p = 0; p < 10; ++p) sqk2 += PMf[p] * S[8 + p] * S[18 + p];
        float* ss = ssum + (blockIdx.x & SMASK) * 48;
        atomicAdd(&ss[g], sqk);
        atomicAdd(&ss[8 + g], 0.1f * S[28]);
        atomicAdd(&ss[16 + g], 0.1f * S[29]);
        atomicAdd(&ss[SIM_CH + g], sqk2);
        atomicAdd(&ss[SIM_CH + 8 + g], 0.01f * S[30]);
        atomicAdd(&ss[SIM_CH + 16 + g], 0.01f * S[31]);
    }
}

// ---- attention (session best, R13): f32 score tables + v2f tree, bf16 sve
// ---- tables, bf16-packed qkv row input (2 uint4) and bf16-packed output -----
__global__ __launch_bounds__(256) void k_attn(const unsigned* __restrict__ qkvp,
                                              const float* __restrict__ qcoef,
                                              const float* __restrict__ scoef,
                                              const float4* __restrict__ TQF,
                                              const uint4* __restrict__ TVB,
                                              unsigned* __restrict__ svp,
                                              float* __restrict__ osums) {
    __shared__ float4 TQs[224];        // f32 [0,112)=q-tab, [112,224)=k-tab
    __shared__ uint4  Tvb[112];        // bf16 {ta0..3, tb0..3}
    __shared__ float4 KVs[4 * 168];    // per-wave: kh[56] | vh[56] | wh[56]
    const int t = threadIdx.x;
    const int wid = t >> 6, lane = t & 63;
    const int unit = blockIdx.x * 4 + wid;
    const int b = unit >> 3, g = unit & 7;
    const int iL = lane < 56 ? lane : 55;

    if (t < 224) TQs[t] = TQF[t];
    if (t < 112) Tvb[t] = TVB[t];      // overlapping range: 2 loads for t<112

    const unsigned* rowp = qkvp + b * 3584 + iL * 64 + g * 8;
    uint4 A  = *(const uint4*)(rowp);        // q pairs, k pairs
    uint4 Bv = *(const uint4*)(rowp + 4);    // v pairs, w pairs
    const float4 a0 = *(const float4*)&qcoef[g * 16];
    const float4 a1 = *(const float4*)&qcoef[g * 16 + 4];
    const float4 a2 = *(const float4*)&qcoef[g * 16 + 8];
    const float4 a3 = *(const float4*)&qcoef[g * 16 + 12];
    const float4 c0 = *(const float4*)&qcoef[QKV_CH + g * 16];
    const float4 c1 = *(const float4*)&qcoef[QKV_CH + g * 16 + 4];
    const float4 c2 = *(const float4*)&qcoef[QKV_CH + g * 16 + 8];
    const float4 c3 = *(const float4*)&qcoef[QKV_CH + g * 16 + 12];
    float4 kh, vh, wh;
    kh.x = blo(A.z) * a1.x + c1.x;  kh.y = bhi(A.z) * a1.y + c1.y;
    kh.z = blo(A.w) * a1.z + c1.z;  kh.w = bhi(A.w) * a1.w + c1.w;
    vh.x = blo(Bv.x) * a2.x + c2.x; vh.y = bhi(Bv.x) * a2.y + c2.y;
    vh.z = blo(Bv.y) * a2.z + c2.z; vh.w = bhi(Bv.y) * a2.w + c2.w;
    wh.x = blo(Bv.z) * a3.x + c3.x; wh.y = bhi(Bv.z) * a3.y + c3.y;
    wh.z = blo(Bv.w) * a3.z + c3.z; wh.w = bhi(Bv.w) * a3.w + c3.w;
    float qh[4];
    qh[0] = blo(A.x) * a0.x + c0.x;  qh[1] = bhi(A.x) * a0.y + c0.y;
    qh[2] = blo(A.y) * a0.z + c0.z;  qh[3] = bhi(A.y) * a0.w + c0.w;

    // stage k/v/w for broadcast reads (lanes 56..63 duplicate slot 55: benign)
    KVs[wid * 168 + iL]       = kh;
    KVs[wid * 168 + 56 + iL]  = vh;
    KVs[wid * 168 + 112 + iL] = wh;
    __syncthreads();

    const float L2E = 1.44269504088896340736f;
    const float aqk = scoef[g] * L2E;
    const float aqr = scoef[8 + g] * 0.1f * L2E;
    const float akr = scoef[16 + g] * 0.1f * L2E;
    const float cc2 = (scoef[SIM_CH + g] + scoef[SIM_CH + 8 + g]
                       + scoef[SIM_CH + 16 + g]) * L2E;
    const v2f qa01 = {qh[0] * aqk, qh[1] * aqk};
    const v2f qa23 = {qh[2] * aqk, qh[3] * aqk};
    const v2f qr01 = {qh[0] * aqr, qh[1] * aqr};
    const v2f qr23 = {qh[2] * aqr, qh[3] * aqr};
    const v2f akrp = {akr, akr};

    float l = 0.f;
    v2f sva = (v2f)(0.f), svb = (v2f)(0.f), svc = (v2f)(0.f), svd = (v2f)(0.f);
    float se0 = 0.f, se1 = 0.f, se2 = 0.f, se3 = 0.f;
    float se4 = 0.f, se5 = 0.f, se6 = 0.f, se7 = 0.f;

    const float4* tqp = TQs + 55 + iL;
    const uint4*  Bp  = Tvb + 55 + iL;
    const float4* kvp = KVs + wid * 168;

#pragma unroll 4
    for (int j = 0; j < 56; ++j) {
        float4 tq = tqp[-j];
        float4 tk = tqp[112 - j];
        uint4  B  = Bp[-j];
        float4 kj = kvp[j];
        float4 vj = kvp[56 + j];
        float4 wj = kvp[112 + j];
        v2f u01 = akrp * (v2f){tk.x, tk.y} + qa01;
        v2f u23 = akrp * (v2f){tk.z, tk.w} + qa23;
        v2f acc = u01 * (v2f){kj.x, kj.y};
        acc += u23 * (v2f){kj.z, kj.w};
        acc += qr01 * (v2f){tq.x, tq.y};
        acc += qr23 * (v2f){tq.z, tq.w};
        float e = EXP2(acc.x + acc.y + cc2);
        l += e;
        v2f ep = {e, e};
        sva += ep * (v2f){vj.x, vj.y};
        svb += ep * (v2f){vj.z, vj.w};
        svc += ep * (v2f){wj.x, wj.y};
        svd += ep * (v2f){wj.z, wj.w};
        se0 += e * blo(B.x); se1 += e * bhi(B.x);
        se2 += e * blo(B.y); se3 += e * bhi(B.y);
        se4 += e * blo(B.z); se5 += e * bhi(B.z);
        se6 += e * blo(B.w); se7 += e * bhi(B.w);
    }
    const float inv = 1.f / l;
    const float inv1 = 0.1f * inv;
    float osv[8], ose[8];
    osv[0] = sva.x * inv;  osv[1] = sva.y * inv;
    osv[2] = svb.x * inv;  osv[3] = svb.y * inv;
    osv[4] = svc.x * inv;  osv[5] = svc.y * inv;
    osv[6] = svd.x * inv;  osv[7] = svd.y * inv;
    ose[0] = se0 * inv1; ose[1] = se1 * inv1;
    ose[2] = se2 * inv1; ose[3] = se3 * inv1;
    ose[4] = se4 * inv1; ose[5] = se5 * inv1;
    ose[6] = se6 * inv1; ose[7] = se7 * inv1;

    if (lane < 56) {
        size_t base = ((size_t)(g * 8) * 1792 + b) * 56 + iL;
#pragma unroll
        for (int c = 0; c < 8; ++c)
            svp[base + (size_t)c * 100352] = pk2(osv[c], ose[c]);
    }
    const float valid = lane < 56 ? 1.f : 0.f;
    float red[32];
#pragma unroll
    for (int c = 0; c < 8; ++c) {
        red[c]      = osv[c] * valid;
        red[8 + c]  = ose[c] * valid;
        red[16 + c] = osv[c] * osv[c] * valid;
        red[24 + c] = ose[c] * ose[c] * valid;
    }
    // explicit halving tree; lane L ends holding full sum of S[bitrev5(L&31)]
    HTREE_STEP(1, 16)
    HTREE_STEP(2, 8)
    HTREE_STEP(4, 4)
    HTREE_STEP(8, 2)
    HTREE_STEP(16, 1)
    red[0] += __shfl_xor(red[0], 32);
    if (lane < 32) {
        const int v = ((lane & 1) << 4) | ((lane & 2) << 2) | (lane & 4)
                    | ((lane & 8) >> 2) | ((lane & 16) >> 4);
        const int addr = ((v >> 4) & 1) * 128 + g * 16 + 2 * (v & 7) + ((v >> 3) & 1);
        float* dst = osums + (blockIdx.x & SMASK) * 256;
        atomicAdd(&dst[addr], red[0]);
    }
}

// ---- out: streaming affine combine from bf16-packed {sv,sve}, coalesced -----
__global__ __launch_bounds__(256) void k_out(const unsigned* __restrict__ svp,
                                             const float* __restrict__ ocoef,
                                             float* __restrict__ out) {
    int e4 = blockIdx.x * 256 + threadIdx.x;
    int i0 = e4 * 4;
    int oc = i0 / 100352;
    int o0 = 2 * oc;
    float A = ocoef[o0], B = ocoef[o0 + 1];
    float C = ocoef[QKV_CH + o0] + ocoef[QKV_CH + o0 + 1];
    uint4 p = *(const uint4*)&svp[i0];
    float4 r;
    r.x = A * blo(p.x) + B * bhi(p.x) + C;
    r.y = A * blo(p.y) + B * bhi(p.y) + C;
    r.z = A * blo(p.z) + B * bhi(p.z) + C;
    r.w = A * blo(p.w) + B * bhi(p.w) + C;
    *(float4*)&out[i0] = r;
}

extern "C" void kernel_launch(void* const* d_in, const int* in_sizes, int n_in,
                              void* d_out, int out_size, void* d_ws, size_t ws_size,
                              hipStream_t stream) {
    const float* x     = (const float*)d_in[0];
    const float* wqkv  = (const float*)d_in[1];
    const float* rel   = (const float*)d_in[2];
    const float* g_qkv = (const float*)d_in[3];
    const float* b_qkv = (const float*)d_in[4];
    const float* g_sim = (const float*)d_in[5];
    const float* b_sim = (const float*)d_in[6];
    const float* g_out = (const float*)d_in[7];
    const float* b_out = (const float*)d_in[8];
    float* out = (float*)d_out;
    float* ws = (float*)d_ws;

    unsigned* qkvp = (unsigned*)ws;             // bf16-packed qkv 6,422,528 uints
    unsigned* svp  = (unsigned*)(ws + 6422528); // packed {sv,sve}  6,422,528
    float* stats   = ws + 12845056;
    float* qkv_sums = stats;                    // 64 x 256 = 16384
    float* sim_sums = stats + 16384;            // 64 x 48  =  3072
    float* out_sums = stats + 19456;            // 64 x 256 = 16384  (ends 35840)
    float* qkv_coef = stats + 35840;            // 256
    float* sim_coef = stats + 36096;            // 48
    float* out_coef = stats + 36144;            // 256   (ends 36400)
    float* tabs     = stats + 36400;            // Rq(224) Rk(224) E2q(672) E2k(672)
                                                // TQF(896) TVB(448) = 3136
    float* Rq   = tabs;
    float* Rk   = tabs + 224;
    float* E2q  = tabs + 448;
    float* E2k  = tabs + 1120;
    float4* TQF = (float4*)(tabs + 1792);
    uint4*  TVB = (uint4*)(tabs + 2688);

    // single upfront memset covers all three de-contended sum buffers
    hipMemsetAsync(stats, 0, 35840 * sizeof(float), stream);

    k_qkv<<<NB + 8, 256, 0, stream>>>(x, wqkv, rel, qkvp, qkv_sums, tabs);
    k_coef<<<QKV_CH, 64, 0, stream>>>(qkv_sums, g_qkv, b_qkv, qkv_coef, QKV_CH,
                                      1.0f / 100352.0f);
    k_simstats<<<3584, 256, 0, stream>>>(qkvp, qkv_coef, Rq, Rk, E2q, E2k,
                                         sim_sums);
    k_coef<<<SIM_CH, 64, 0, stream>>>(sim_sums, g_sim, b_sim, sim_coef, SIM_CH,
                                      1.0f / 5619712.0f);
    k_attn<<<3584, 256, 0, stream>>>(qkvp, qkv_coef, sim_coef, TQF, TVB,
                                     svp, out_sums);
    k_coef<<<QKV_CH, 64, 0, stream>>>(out_sums, g_out, b_out, out_coef, QKV_CH,
                                      1.0f / 100352.0f);
    k_out<<<6272, 256, 0, stream>>>(svp, out_coef, out);
}